// Round 11
// baseline (524.478 us; speedup 1.0000x reference)
//
#include <hip/hip_runtime.h>

typedef unsigned short u16;
typedef __attribute__((ext_vector_type(8))) short short8;
typedef __attribute__((ext_vector_type(4))) float floatx4;

__device__ inline float bf2f(u16 v){ union { unsigned int i; float f; } u; u.i = ((unsigned int)v) << 16; return u.f; }
// RNE f32->bf16 via compiler cast: lowers to v_cvt_pk_bf16_f32 on gfx950
// (bit-identical to the integer round-half-even trick, fewer VALU ops).
__device__ inline u16 f2bf(float f){ union { __bf16 b; u16 s; } u; u.b = (__bf16)f; return u.s; }
__device__ inline float sigmf(float x){ return 1.f/(1.f + __expf(-x)); }
__device__ inline float tanhfast(float x){ float e = __expf(-2.f*fabsf(x)); float t = (1.f-e)/(1.f+e); return x>=0.f? t : -t; }
__device__ inline float wred(float x){ for (int o = 32; o; o >>= 1) x += __shfl_xor(x, o); return x; }
__device__ inline float hred32(float x){ for (int o = 16; o; o >>= 1) x += __shfl_xor(x, o); return x; }

// dual-dtype scalar load: fl==1 -> buffer is float32, else bf16(u16)
__device__ inline float ldf(const void* p, long i, int fl){
  return fl ? ((const float*)p)[i] : bf2f(((const u16*)p)[i]);
}
// paired load at EVEN index (alignment guaranteed by caller)
__device__ inline float2 ldf2(const void* p, long i, int fl){
  if (fl) return *(const float2*)((const float*)p + i);
  unsigned int v = *(const unsigned int*)((const u16*)p + i);
  float2 r; r.x = bf2f((u16)(v & 0xffffu)); r.y = bf2f((u16)(v >> 16)); return r;
}
// 8-element load -> bf16 frag. mode: 0=bf16 buffer, 1=follow fl, 2=f32 buffer
__device__ inline short8 ld8m(const void* p, long i, int mode, int fl){
  int isf = (mode == 2) || (mode == 1 && fl);
  if (!isf) return *(const short8*)((const u16*)p + i);
  const float* f = (const float*)p + i;
  float4 x = *(const float4*)f;
  float4 y = *(const float4*)(f + 4);
  short8 r;
  r[0]=(short)f2bf(x.x); r[1]=(short)f2bf(x.y); r[2]=(short)f2bf(x.z); r[3]=(short)f2bf(x.w);
  r[4]=(short)f2bf(y.x); r[5]=(short)f2bf(y.y); r[6]=(short)f2bf(y.z); r[7]=(short)f2bf(y.w);
  return r;
}

#define MFMA(a,b,c) __builtin_amdgcn_mfma_f32_16x16x32_bf16(a,b,c,0,0,0)
#define LDW 40   // LDS tile row stride in shorts (80B): breaks the 64B-stride 8-way bank alias

// ---------------------------------------------------------------------------
__global__ void detect_kernel(const u16* __restrict__ w, int* __restrict__ flag){
  __shared__ int cnt[256];
  int t = threadIdx.x, c = 0;
  for (int i = t; i < 4096; i += 256){ u16 v = w[i]; if ((v & 0x7fff) >= 0x4200) c++; }
  cnt[t] = c; __syncthreads();
  for (int s = 128; s; s >>= 1){ if (t < s) cnt[t] += cnt[t + s]; __syncthreads(); }
  if (t == 0) *flag = (cnt[0] > 16) ? 1 : 0;
}

// ---------------------------------------------------------------------------
// shared transpose tile body: out[n][k] = (k<K)? in[ro+k][n] : 0
__device__ inline void tbody(float (*tile)[33], const void* in, int ldin, int ro,
                             int K, int N, int Kpad, u16* out, int fl, int k0, int n0)
{
  int tx = threadIdx.x & 31, ty = threadIdx.x >> 5;   // 32 x 8
  for (int i = ty; i < 32; i += 8){
    int k = k0 + i, n = n0 + tx;
    tile[i][tx] = (k < K && n < N) ? ldf(in, (long)(ro + k)*ldin + n, fl) : 0.f;
  }
  __syncthreads();
  for (int i = ty; i < 32; i += 8){
    int n = n0 + i, k = k0 + tx;
    if (n < N && k < Kpad) out[(long)n*Kpad + k] = f2bf(tile[tx][i]);
  }
}

// early fused transpose + bc: Wov (y<4), Wav (y<6), Wev (y<9),
// bc (y in [9,13): 32 virtual bc-blocks of 16 j-cols). grid (8,13)
__global__ __launch_bounds__(256) void transpose3a_kernel(
    const void* __restrict__ Wov, const void* __restrict__ Wav, const void* __restrict__ Wev,
    u16* __restrict__ WovT, u16* __restrict__ WavT, u16* __restrict__ WevT,
    const void* __restrict__ Wa1, const void* __restrict__ be2,
    const void* __restrict__ ba1, float* __restrict__ bc,
    const int* __restrict__ flg)
{
  const int fl = *flg;
  __shared__ float tile[32][33];
  int y = blockIdx.y, n0 = blockIdx.x*32;
  if (y < 4)      tbody(tile, Wov, 256, 0, 128, 256, 128, WovT, fl, y*32, n0);
  else if (y < 6) tbody(tile, Wav, 256, 0,  64, 256,  64, WavT, fl, (y-4)*32, n0);
  else if (y < 9) tbody(tile, Wev, 256, 0,  65, 256,  96, WevT, fl, (y-6)*32, n0);
  else {
    // ---- bc (R6-proven body): bc[j] = ba1[j] + sum_c be2[c]*Wa1[c,j] (top) ----
    __shared__ float red[16][17];
    const int t = threadIdx.x;
    const int jj = t & 15, cs = t >> 4;
    const int jb = ((y - 9)*8 + blockIdx.x)*16;
    const int j = jb + jj;
    float acc = 0.f;
    for (int c = cs*32; c < cs*32 + 32; c++)
      acc = fmaf(ldf(be2, c, fl), ldf(Wa1, (long)c*512 + j, fl), acc);
    red[jj][cs] = acc;
    __syncthreads();
    if (t < 16){
      float s = ldf(ba1, jb + t, fl);
      #pragma unroll
      for (int k = 0; k < 16; k++) s += red[t][k];
      bc[jb + t] = s;
    }
  }
}

// late fused transpose + wo head: Wa1 bottom (y<16), Wa1 top (y<32),
// We1 (y<35), wo out[:,0:6] (y in [35,39)). grid (16,39); runs after gru.
__global__ __launch_bounds__(256) void transpose3b_kernel(
    const void* __restrict__ Wa1, const void* __restrict__ We1,
    u16* __restrict__ Wa1bT, u16* __restrict__ Wa1tT, u16* __restrict__ We1T,
    const float* __restrict__ h, const void* __restrict__ Wwo,
    const void* __restrict__ bwo, float* __restrict__ out,
    const int* __restrict__ flg)
{
  const int fl = *flg;
  __shared__ float tile[32][33];
  int y = blockIdx.y, n0 = blockIdx.x*32;
  if (y < 16)      tbody(tile, Wa1, 512, 512, 512, 512, 512, Wa1bT, fl, y*32, n0);
  else if (y < 32) tbody(tile, Wa1, 512, 0,   512, 512, 512, Wa1tT, fl, (y-16)*32, n0);
  else if (y < 35) tbody(tile, We1, 512, 0,    65, 512,  96, We1T,  fl, (y-32)*32, n0);
  else {
    // ---- fused wo (R0-proven body): out[:,0:6] = h @ Wwo + bwo ----
    __shared__ float red[64][4][6];
    const int t = threadIdx.x, r = t >> 2, kq = t & 3;
    const long b = (long)((y - 35)*16 + blockIdx.x)*64 + r;
    float acc[6] = {};
    for (int k = kq*128; k < kq*128 + 128; k++){
      float hv = h[b*512 + k];
      #pragma unroll
      for (int j = 0; j < 6; j++) acc[j] = fmaf(hv, ldf(Wwo, (long)k*6 + j, fl), acc[j]);
    }
    #pragma unroll
    for (int j = 0; j < 6; j++) red[r][kq][j] = acc[j];
    __syncthreads();
    if (kq == 0){
      #pragma unroll
      for (int j = 0; j < 6; j++)
        out[b*38 + j] = red[r][0][j] + red[r][1][j] + red[r][2][j] + red[r][3][j] + ldf(bwo, j, fl);
    }
  }
}

// ---------------------------------------------------------------------------
// Fused U-construct + WGT GEMM + bG reduce. grid (3,2), 256 thr.
// A-tiles (U rows: 0..63=Wak, 64=bak, 65..129=Wek, 130=bek, rest 0) are built
// in registers with the same f2bf rounding the old U buffer had; bG[c] =
// bq . U[c,:] accumulated from the same register values (y==0 blocks).
// U is never materialized; WGT[c,d] = sum_a U[c,a]*Wq[d,a] (bf16 out).
__global__ __launch_bounds__(256) void build_uwgt_kernel(
    const void* __restrict__ Wak, const void* __restrict__ bak,
    const void* __restrict__ Wek, const void* __restrict__ bek,
    const void* __restrict__ bq, const void* __restrict__ Wq,
    u16* __restrict__ WGT, float* __restrict__ bG, const int* __restrict__ flg)
{
  const int fl = *flg;
  __shared__ __align__(16) short Al[64*LDW];
  __shared__ __align__(16) short Bl[64*LDW];
  __shared__ float redg[64][4];
  const int t = threadIdx.x, lane = t & 63, w = t >> 6;
  const int m0 = blockIdx.x*64, n0 = blockIdx.y*64;
  floatx4 acc[4] = {};
  const int row = t >> 2, seg = t & 3;
  const int c = m0 + row;
  float pg = 0.f;
  for (int kt = 0; kt < 128; kt += 32){
    __syncthreads();
    short8 av;
    #pragma unroll
    for (int j = 0; j < 8; j++){
      int a = kt + seg*8 + j;
      float v = 0.f;
      if (c < 64)        v = ldf(Wak, (long)c*128 + a, fl);
      else if (c == 64)  v = ldf(bak, a, fl);
      else if (c < 130)  v = ldf(Wek, (long)(c-65)*128 + a, fl);
      else if (c == 130) v = ldf(bek, a, fl);
      av[j] = (short)f2bf(v);
    }
    *(short8*)(Al + row*LDW + seg*8) = av;
    if (blockIdx.y == 0){
      #pragma unroll
      for (int j = 0; j < 8; j++)
        pg = fmaf(ldf(bq, kt + seg*8 + j, fl), bf2f((u16)av[j]), pg);
    }
    *(short8*)(Bl + row*LDW + seg*8) = ld8m(Wq, (long)(n0 + row)*128 + kt + seg*8, 1, fl);
    __syncthreads();
    short8 a = *(const short8*)(Al + (w*16 + (lane & 15))*LDW + ((lane >> 4)*8));
    #pragma unroll
    for (int nt = 0; nt < 4; nt++){
      short8 b = *(const short8*)(Bl + (nt*16 + (lane & 15))*LDW + ((lane >> 4)*8));
      acc[nt] = MFMA(a, b, acc[nt]);
    }
  }
  #pragma unroll
  for (int nt = 0; nt < 4; nt++){
    int col = n0 + nt*16 + (lane & 15);
    #pragma unroll
    for (int i = 0; i < 4; i++){
      int r = m0 + w*16 + (lane >> 4)*4 + i;
      WGT[(long)r*128 + col] = f2bf(acc[nt][i]);
    }
  }
  if (blockIdx.y == 0){
    redg[row][seg] = pg;
    __syncthreads();
    if (t < 64) bG[m0 + t] = redg[t][0] + redg[t][1] + redg[t][2] + redg[t][3];
  }
}

// ---------------------------------------------------------------------------
// shared MFMA GEMM body: out[r, ocol+col] = A[M,K(lda)] @ B[N,K]^T + bias.
// LDS tiles padded to LDW=40 shorts/row (bank-conflict fix).
__device__ inline void gemm_body(const void* A, int lda, const void* Bm,
    const float* bias, u16* outp, int ldout, int ocol, int K, int fl,
    int amode, int bmode, short* Al, short* Bl)
{
  const int t = threadIdx.x, lane = t & 63, w = t >> 6;
  const int m0 = blockIdx.x*64, n0 = blockIdx.y*64;
  floatx4 acc[4] = {};
  const int row = t >> 2, seg = t & 3;
  for (int kt = 0; kt < K; kt += 32){
    __syncthreads();
    *(short8*)(Al + row*LDW + seg*8) = ld8m(A,  (long)(m0 + row)*lda + kt + seg*8, amode, fl);
    *(short8*)(Bl + row*LDW + seg*8) = ld8m(Bm, (long)(n0 + row)*K   + kt + seg*8, bmode, fl);
    __syncthreads();
    short8 a = *(const short8*)(Al + (w*16 + (lane & 15))*LDW + ((lane >> 4)*8));
    #pragma unroll
    for (int nt = 0; nt < 4; nt++){
      short8 b = *(const short8*)(Bl + (nt*16 + (lane & 15))*LDW + ((lane >> 4)*8));
      acc[nt] = MFMA(a, b, acc[nt]);
    }
  }
  #pragma unroll
  for (int nt = 0; nt < 4; nt++){
    int col = n0 + nt*16 + (lane & 15);
    float bb = bias ? bias[col] : 0.f;
    #pragma unroll
    for (int i = 0; i < 4; i++){
      int r = m0 + w*16 + (lane >> 4)*4 + i;
      outp[(long)r*ldout + ocol + col] = f2bf(acc[nt][i] + bb);
    }
  }
}

// fused tot builder: z=0 own@WovT (K=128), z=1 mixa@WavT (K=64), z=2 mixe@WevT (K=96)
__global__ __launch_bounds__(256) void gemm_tot_kernel(
    const void* __restrict__ own, const u16* __restrict__ mixbuf,
    const u16* __restrict__ WovT, const u16* __restrict__ WavT, const u16* __restrict__ WevT,
    u16* __restrict__ tot, const int* __restrict__ flg)
{
  const int fl = *flg;
  __shared__ __align__(16) short Al[64*LDW];
  __shared__ __align__(16) short Bl[64*LDW];
  const void* A; const u16* Bm; int lda, K, ocol, amode;
  if (blockIdx.z == 0){ A = own;         lda = 128; Bm = WovT; K = 128; ocol = 0;   amode = 1; }
  else if (blockIdx.z == 1){ A = mixbuf; lda = 160; Bm = WavT; K = 64;  ocol = 256; amode = 0; }
  else { A = mixbuf + 64;                lda = 160; Bm = WevT; K = 96;  ocol = 512; amode = 0; }
  gemm_body(A, lda, Bm, nullptr, tot, 768, ocol, K, fl, amode, 0, Al, Bl);
}

// fused post-transpose GEMMs: z=0 u = h @ Wa1_bot + bc (64x8 blocks),
// z=1 Wc = We2 @ Wa1_top (8x8 blocks, extra x-blocks return). grid (64,8,2)
__global__ __launch_bounds__(256) void gemm_post_kernel(
    const float* __restrict__ h, const u16* __restrict__ Wa1bT, const float* __restrict__ bc,
    u16* __restrict__ u_b, const u16* __restrict__ Wa1tT, const void* __restrict__ We2,
    u16* __restrict__ WcT, const int* __restrict__ flg)
{
  const int fl = *flg;
  __shared__ __align__(16) short Al[64*LDW];
  __shared__ __align__(16) short Bl[64*LDW];
  if (blockIdx.z == 0){
    gemm_body(h, 512, Wa1bT, bc, u_b, 512, 0, 512, fl, 2, 0, Al, Bl);
  } else {
    if (blockIdx.x >= 8) return;
    gemm_body(Wa1tT, 512, We2, nullptr, WcT, 512, 0, 512, fl, 0, 1, Al, Bl);
  }
}

// ---------------------------------------------------------------------------
// Attention + inline G: each block computes its own 8x192 G-slice
// (G = own @ WGT^T + bG, bf16-rounded to match the old store/load path),
// then runs the R7-proven two-rows-per-wave attention body.
// WGT staged to LDS at word-stride 65 (row 130 shorts): column reads across
// consecutive c hit distinct banks. own rows bf16-rounded (matches old amode=1).
__global__ __launch_bounds__(256) void attn_kernel(
    const void* __restrict__ own, const u16* __restrict__ WGT,
    const float* __restrict__ bG,
    const void* __restrict__ af, const void* __restrict__ ef,
    u16* __restrict__ mixbuf, const int* __restrict__ flg)
{
  const int fl = *flg;
  __shared__ __align__(4) u16 wgt_l[192*130];
  __shared__ float own_l[8][128];
  __shared__ float gsh[8][192];
  __shared__ float attw[8][32];
  const int t = threadIdx.x;
  const int lane = t & 63, wv = t >> 6;
  const int l = lane & 31, hi = lane >> 5;
  const int wr = wv*2 + hi;
  const long b = (long)blockIdx.x*8 + wr;
  const float rsA = 0.08838834764831845f;  // 1/sqrt(128)

  // ---- stage WGT [192][128] -> LDS word-stride 65; own rows (bf16-rounded)
  for (int idx = t; idx < 192*64; idx += 256){
    int row = idx >> 6, cw = idx & 63;
    ((unsigned int*)wgt_l)[row*65 + cw] = *(const unsigned int*)(WGT + row*128 + cw*2);
  }
  for (int idx = t; idx < 8*128; idx += 256){
    int r = idx >> 7, a = idx & 127;
    own_l[r][a] = bf2f(f2bf(ldf(own, ((long)blockIdx.x*8 + r)*128 + a, fl)));
  }
  __syncthreads();

  // ---- compute G rows: gsh[r][c] = bf16round(own_l[r,:].WGT[c,:] + bG[c])
  #pragma unroll
  for (int o = 0; o < 6; o++){
    int flat = t + o*256;
    int r = flat / 192, c = flat - r*192;
    float acc = bG[c];
    #pragma unroll
    for (int a = 0; a < 128; a += 2){
      unsigned int wvv = ((unsigned int*)wgt_l)[c*65 + (a >> 1)];
      acc = fmaf(own_l[r][a],   bf2f((u16)(wvv & 0xffffu)), acc);
      acc = fmaf(own_l[r][a+1], bf2f((u16)(wvv >> 16)), acc);
    }
    gsh[r][c] = bf2f(f2bf(acc));
  }
  __syncthreads();

  // ---- allies ----
  float2 qa2; qa2.x = gsh[wr][2*l]; qa2.y = gsh[wr][2*l + 1];
  float sa = gsh[wr][64];
  float2 fva[31];
  float myE = -1e30f;
  #pragma unroll
  for (int n = 0; n < 31; n++){
    fva[n] = ldf2(af, ((long)n*4096 + b)*64 + 2*l, fl);
    float e = hred32(fva[n].x*qa2.x + fva[n].y*qa2.y);
    e = (e + sa) * rsA;
    if (l == n) myE = e;
  }
  {
    float m = myE;
    for (int o = 16; o; o >>= 1) m = fmaxf(m, __shfl_xor(m, o));
    float p = (l < 31) ? __expf(myE - m) : 0.f;
    float s = hred32(p);
    attw[wr][l] = p / s;
  }
  __syncthreads();
  {
    float2 acc = {0.f, 0.f};
    #pragma unroll
    for (int n = 0; n < 31; n++){
      float w = attw[wr][n];
      acc.x = fmaf(w, fva[n].x, acc.x);
      acc.y = fmaf(w, fva[n].y, acc.y);
    }
    unsigned int pk = (unsigned int)f2bf(acc.x) | ((unsigned int)f2bf(acc.y) << 16);
    *(unsigned int*)(mixbuf + b*160 + 2*l) = pk;
  }
  __syncthreads();

  // ---- enemies (65 dims: d=2l,2l+1 per lane; lane 0 adds d=64) ----
  float2 qe2; qe2.x = gsh[wr][65 + 2*l]; qe2.y = gsh[wr][66 + 2*l];
  float qe64 = gsh[wr][129];
  float se = gsh[wr][130];
  float2 fve[32];
  myE = -1e30f;
  #pragma unroll
  for (int n = 0; n < 32; n++){
    long base = ((long)n*4096 + b)*65;
    fve[n].x = ldf(ef, base + 2*l, fl);
    fve[n].y = ldf(ef, base + 2*l + 1, fl);
    float prod = fve[n].x*qe2.x + fve[n].y*qe2.y;
    if (l == 0) prod = fmaf(ldf(ef, base + 64, fl), qe64, prod);
    float e = (hred32(prod) + se) * rsA;
    if (l == n) myE = e;
  }
  {
    float m = myE;
    for (int o = 16; o; o >>= 1) m = fmaxf(m, __shfl_xor(m, o));
    float p = __expf(myE - m);
    float s = hred32(p);
    attw[wr][l] = p / s;
  }
  __syncthreads();
  {
    float2 acc = {0.f, 0.f};
    float acc64 = 0.f;
    #pragma unroll
    for (int n = 0; n < 32; n++){
      long base = ((long)n*4096 + b)*65;
      float w = attw[wr][n];
      acc.x = fmaf(w, fve[n].x, acc.x);
      acc.y = fmaf(w, fve[n].y, acc.y);
      if (l == 0) acc64 = fmaf(w, ldf(ef, base + 64, fl), acc64);
    }
    unsigned int pk = (unsigned int)f2bf(acc.x) | ((unsigned int)f2bf(acc.y) << 16);
    *(unsigned int*)(mixbuf + b*160 + 64 + 2*l) = pk;
    if (l == 0) mixbuf[b*160 + 128] = f2bf(acc64);
    if (l >= 1) mixbuf[b*160 + 128 + l] = 0;
  }
}

// ---------------------------------------------------------------------------
// GRU: block = 128 batch rows x 64 hidden cols (512 thr); h (f32) -> d_out.
// 1-D grid of 256 with XCD swizzle: j0 = (bid&7)*64 -> per-XCD weight
// footprint ~1MB (L2-hot). LDS tiles padded to LDW=40.
__global__ __launch_bounds__(512) void gru_kernel(
    const u16* __restrict__ tot, const void* __restrict__ hprev,
    const void* __restrict__ w_ih, const void* __restrict__ w_hh,
    const void* __restrict__ b_ih, const void* __restrict__ b_hh,
    float* __restrict__ h_out, const int* __restrict__ flg)
{
  const int fl = *flg;
  __shared__ __align__(16) short At[128*LDW], Ah[128*LDW];
  __shared__ __align__(16) short Bi[3][64*LDW], Bh[3][64*LDW];
  const int t = threadIdx.x, lane = t & 63, w = t >> 6;
  const int bid = blockIdx.x;
  const int b0 = (bid >> 3)*128, j0 = (bid & 7)*64;
  floatx4 ai[3][4] = {}; floatx4 ah[3][4] = {};
  const int row = t >> 2, seg = t & 3;
  for (int kt = 0; kt < 768; kt += 32){
    __syncthreads();
    *(short8*)(At + row*LDW + seg*8) = *(const short8*)(tot + (long)(b0 + row)*768 + kt + seg*8);
    if (kt < 512)
      *(short8*)(Ah + row*LDW + seg*8) = ld8m(hprev, (long)(b0 + row)*512 + kt + seg*8, 1, fl);
    if (t < 256){
      int rb = t >> 2, sb = t & 3;
      #pragma unroll
      for (int p = 0; p < 3; p++)
        *(short8*)(Bi[p] + rb*LDW + sb*8) = ld8m(w_ih, (long)(p*512 + j0 + rb)*768 + kt + sb*8, 1, fl);
    } else if (kt < 512){
      int t2 = t - 256, rb = t2 >> 2, sb = t2 & 3;
      #pragma unroll
      for (int p = 0; p < 3; p++)
        *(short8*)(Bh[p] + rb*LDW + sb*8) = ld8m(w_hh, (long)(p*512 + j0 + rb)*512 + kt + sb*8, 1, fl);
    }
    __syncthreads();
    short8 a = *(const short8*)(At + (w*16 + (lane & 15))*LDW + ((lane >> 4)*8));
    #pragma unroll
    for (int p = 0; p < 3; p++){
      #pragma unroll
      for (int nt = 0; nt < 4; nt++){
        short8 b = *(const short8*)(Bi[p] + (nt*16 + (lane & 15))*LDW + ((lane >> 4)*8));
        ai[p][nt] = MFMA(a, b, ai[p][nt]);
      }
    }
    if (kt < 512){
      short8 a2 = *(const short8*)(Ah + (w*16 + (lane & 15))*LDW + ((lane >> 4)*8));
      #pragma unroll
      for (int p = 0; p < 3; p++){
        #pragma unroll
        for (int nt = 0; nt < 4; nt++){
          short8 b = *(const short8*)(Bh[p] + (nt*16 + (lane & 15))*LDW + ((lane >> 4)*8));
          ah[p][nt] = MFMA(a2, b, ah[p][nt]);
        }
      }
    }
  }
  #pragma unroll
  for (int nt = 0; nt < 4; nt++){
    int colH = j0 + nt*16 + (lane & 15);
    float bir = ldf(b_ih, colH, fl),        bhr = ldf(b_hh, colH, fl);
    float biz = ldf(b_ih, 512 + colH, fl),  bhz = ldf(b_hh, 512 + colH, fl);
    float bin = ldf(b_ih, 1024 + colH, fl), bhn = ldf(b_hh, 1024 + colH, fl);
    #pragma unroll
    for (int i = 0; i < 4; i++){
      int r = b0 + w*16 + (lane >> 4)*4 + i;
      float rg = sigmf(ai[0][nt][i] + bir + ah[0][nt][i] + bhr);
      float zg = sigmf(ai[1][nt][i] + biz + ah[1][nt][i] + bhz);
      float ng = tanhfast(ai[2][nt][i] + bin + rg*(ah[2][nt][i] + bhn));
      float hp = ldf(hprev, (long)r*512 + colH, fl);
      h_out[(long)r*512 + colH] = (1.f - zg)*ng + zg*hp;
    }
  }
}

// ---------------------------------------------------------------------------
// Head: EXACT R0 structure (151us with cvt_pk f2bf; 6 structural edits all
// null/regressed — frozen).
__global__ __launch_bounds__(512) void head_kernel(
    const void* __restrict__ ef_g, const u16* __restrict__ We1T,
    const void* __restrict__ be1, const u16* __restrict__ WcT,
    const u16* __restrict__ u_b, const void* __restrict__ wa2,
    const void* __restrict__ ba2, float* __restrict__ out, const int* __restrict__ flg)
{
  const int fl = *flg;
  __shared__ __align__(16) short r1s[2][64*512];  // XOR-swizzled: (row, chunk^(row&7))
  __shared__ __align__(16) short efl[64*96];
  __shared__ float part[2][64][9];
  const int t = threadIdx.x, lane = t & 63, w = t >> 6;
  const int m = lane & 15, q = lane >> 4;
  const int n0 = blockIdx.y*2, b0 = blockIdx.x*64;

  // phase 1: r1[e][64][512]; enemies staged sequentially through one efl buffer
  for (int e = 0; e < 2; e++){
    const int n = n0 + e;
    __syncthreads();   // protect efl from previous enemy's readers
    for (int idx = t; idx < 64*96; idx += 512){
      int r = idx / 96, d = idx - r*96;
      u16 v = 0;
      if (d < 65) v = f2bf(ldf(ef_g, ((long)n*4096 + b0 + r)*65 + d, fl));
      efl[idx] = (short)v;
    }
    __syncthreads();
    #pragma unroll
    for (int jt4 = 0; jt4 < 4; jt4++){
      const int coln = (w*4 + jt4)*16 + m;
      short8 bfr[3];
      #pragma unroll
      for (int k3 = 0; k3 < 3; k3++)
        bfr[k3] = *(const short8*)(We1T + coln*96 + k3*32 + q*8);
      float be = ldf(be1, coln, fl);
      const int chunk = coln >> 3, sub = coln & 7;
      #pragma unroll
      for (int rt = 0; rt < 4; rt++){
        floatx4 acc = {0.f, 0.f, 0.f, 0.f};
        #pragma unroll
        for (int k3 = 0; k3 < 3; k3++){
          short8 a = *(const short8*)(efl + (rt*16 + m)*96 + k3*32 + q*8);
          acc = MFMA(a, bfr[k3], acc);
        }
        #pragma unroll
        for (int i = 0; i < 4; i++){
          int row = rt*16 + q*4 + i;
          float v = acc[i] + be;
          r1s[e][row*512 + ((chunk ^ (row & 7)) << 3) + sub] = (short)f2bf(v > 0.f ? v : 0.f);
        }
      }
    }
  }
  __syncthreads();

  // phase 2: wave w -> output cols [w*64, w*64+64); each B-frag used 8x (2e x 4rt)
  floatx4 acc[2][4][4] = {};
  for (int kt = 0; kt < 512; kt += 32){
    short8 b[4];
    #pragma unroll
    for (int js = 0; js < 4; js++)
      b[js] = *(const short8*)(WcT + (long)(w*64 + js*16 + m)*512 + kt + q*8);
    const int ch = (((kt >> 3) + q) ^ (m & 7)) << 3;
    #pragma unroll
    for (int e = 0; e < 2; e++){
      #pragma unroll
      for (int rt = 0; rt < 4; rt++){
        short8 a = *(const short8*)(r1s[e] + (rt*16 + m)*512 + ch);
        #pragma unroll
        for (int js = 0; js < 4; js++)
          acc[e][rt][js] = MFMA(a, b[js], acc[e][rt][js]);
      }
    }
  }

  // epilogue: u_b loaded once, shared across both enemies
  float pr[2][4][4] = {};
  #pragma unroll
  for (int js = 0; js < 4; js++){
    int col = w*64 + js*16 + m;
    float wv = ldf(wa2, col, fl);
    #pragma unroll
    for (int rt = 0; rt < 4; rt++){
      #pragma unroll
      for (int i = 0; i < 4; i++){
        int grow = b0 + rt*16 + q*4 + i;
        float u = bf2f(u_b[(long)grow*512 + col]);
        #pragma unroll
        for (int e = 0; e < 2; e++){
          float s = acc[e][rt][js][i] + u;
          pr[e][rt][i] += (s > 0.f ? s : 0.f) * wv;
        }
      }
    }
  }
  #pragma unroll
  for (int o = 1; o < 16; o <<= 1){
    #pragma unroll
    for (int e = 0; e < 2; e++)
      #pragma unroll
      for (int rt = 0; rt < 4; rt++)
        #pragma unroll
        for (int i = 0; i < 4; i++)
          pr[e][rt][i] += __shfl_xor(pr[e][rt][i], o);
  }
  if (m == 0){
    #pragma unroll
    for (int e = 0; e < 2; e++)
      #pragma unroll
      for (int rt = 0; rt < 4; rt++)
        #pragma unroll
        for (int i = 0; i < 4; i++)
          part[e][rt*16 + q*4 + i][w] = pr[e][rt][i];
  }
  __syncthreads();
  if (t < 128){
    int e = t >> 6, r = t & 63;
    float s = ldf(ba2, 0, fl);
    #pragma unroll
    for (int ww = 0; ww < 8; ww++) s += part[e][r][ww];
    out[(long)(b0 + r)*38 + 6 + n0 + e] = s;
  }
}

// ---------------------------------------------------------------------------
extern "C" void kernel_launch(void* const* d_in, const int* in_sizes, int n_in,
                              void* d_out, int out_size, void* d_ws, size_t ws_size,
                              hipStream_t stream)
{
  (void)in_sizes; (void)n_in; (void)out_size; (void)ws_size;
  const void* own  = d_in[0];
  const void* af   = d_in[1];
  const void* ef   = d_in[2];
  const void* hid  = d_in[3];
  const void* Wq   = d_in[4];
  const void* bq   = d_in[5];
  const void* Wak  = d_in[6];
  const void* bak  = d_in[7];
  const void* Wav  = d_in[8];
  const void* Wek  = d_in[10];
  const void* bek  = d_in[11];
  const void* Wev  = d_in[12];
  const void* Wov  = d_in[14];
  const void* w_ih = d_in[16];
  const void* w_hh = d_in[17];
  const void* b_ih = d_in[18];
  const void* b_hh = d_in[19];
  const void* Wwo  = d_in[20];
  const void* bwo  = d_in[21];
  const void* We1  = d_in[22];
  const void* be1  = d_in[23];
  const void* We2  = d_in[24];
  const void* be2  = d_in[25];
  const void* Wa1  = d_in[26];
  const void* ba1  = d_in[27];
  const void* Wa2  = d_in[28];
  const void* ba2  = d_in[29];
  float* out   = (float*)d_out;                 // q [4096,38] f32
  float* h_out = out + (long)4096*38;           // h [4096,512] f32

  // ---- workspace (7.76 MB peak, time-phased aliasing) ----
  char* ws = (char*)d_ws;
  u16*   tot    = (u16*)(ws + 0);               // [4096,768] bf16 = 6,291,456
  u16*   WGT    = (u16*)(ws + 0);               // [192,128] bf16 (alias, dead before tot)
  u16*   u_b    = (u16*)(ws + 0);               // [4096,512] bf16 = 4 MB (alias, after gru)
  u16*   Wa1tT  = (u16*)(ws + 4194304);         // [512,512] bf16 (tot region tail, post-gru)
  char*  mz     = ws + 6291456;                 // 1,310,720 multi-phase zone
  u16*   mixbuf = (u16*)mz;                     // [4096,160] bf16 (attention phase)
  u16*   Wa1bT  = (u16*)mz;                     // [512,512] bf16 (post-gru phase)
  u16*   WcT    = (u16*)(mz + 524288);          // [512,512] bf16 (post-u phase)
  u16*   We1T   = (u16*)(mz + 1048576);         // [512,96]  bf16 (post-gru phase)
  char*  P      = ws + 7602176;                 // persistent small zone
  u16*   WovT   = (u16*)(P + 0);                // [256,128] bf16
  u16*   WavT   = (u16*)(P + 65536);            // [256,64]  bf16
  u16*   WevT   = (u16*)(P + 98304);            // [256,96]  bf16
  float* bc     = (float*)(P + 147456);         // [512] f32
  float* bG     = (float*)(P + 149504);         // [192] f32
  int*   flg    = (int*)(P + 150528);

  detect_kernel<<<1, 256, 0, stream>>>((const u16*)w_ih, flg);

  // prep: fused V-projection transposes + bc  ||  fused U-construct+WGT+bG
  transpose3a_kernel<<<dim3(8, 13), 256, 0, stream>>>(Wov, Wav, Wev, WovT, WavT, WevT,
                                                      Wa1, be2, ba1, bc, flg);
  build_uwgt_kernel<<<dim3(3, 2), 256, 0, stream>>>(Wak, bak, Wek, bek, bq, Wq, WGT, bG, flg);
  // attention (computes its own G-slice from own/WGT/bG) -> mixbuf
  attn_kernel<<<512, 256, 0, stream>>>(own, WGT, bG, af, ef, mixbuf, flg);
  // tot = [own@Wov | mix_a@Wav | mix_e@Wev]  (one launch; overwrites WGT)
  gemm_tot_kernel<<<dim3(64, 4, 3), 256, 0, stream>>>(own, mixbuf, WovT, WavT, WevT, tot, flg);
  // GRU -> h (f32 in d_out); 1-D grid, XCD-swizzled (j = bid&7)
  gru_kernel<<<256, 512, 0, stream>>>(tot, hid, w_ih, w_hh, b_ih, b_hh, h_out, flg);
  // fused late transposes + wo head (tot + mixbuf dead): Wa1bT@mz, Wa1tT@ws+4MB, We1T
  transpose3b_kernel<<<dim3(16, 39), 256, 0, stream>>>(Wa1, We1, Wa1bT, Wa1tT, We1T,
                                                       h_out, Wwo, bwo, out, flg);
  // u = h @ Wa1_bot + bc -> u_b  ||  Wc = We2 @ Wa1_top  (one z-fused launch)
  gemm_post_kernel<<<dim3(64, 8, 2), 256, 0, stream>>>(h_out, Wa1bT, bc, u_b,
                                                       Wa1tT, We2, WcT, flg);
  // heads
  head_kernel<<<dim3(64, 16), 512, 0, stream>>>(ef, We1T, be1, WcT, u_b, Wa2, ba2, out, flg);
}